// Round 1
// baseline (131.052 us; speedup 1.0000x reference)
//
#include <hip/hip_runtime.h>

// Depthwise cross-correlation: z (64,256,7,7) over x (64,256,31,31) VALID
// -> out (64,256,25,25), scaled by 0.001.
//
// One block per (b,c) slice (16384 blocks, 128 threads).
// Stage x slice (961 f32) + z (49 f32) in LDS. 125 threads each compute a
// 5-wide horizontal output strip: per kernel row, 11 LDS reads feed
// 5 outputs x 7 taps (register reuse cuts LDS ops from 49/out to ~15/out,
// further merged to ds_read2_b32 by the compiler). z held in 49 VGPRs.

#define KH 7
#define KW 7
#define XH 31
#define XW 31
#define OH 25
#define OW 25
#define NSLICE (64 * 256)

__global__ __launch_bounds__(128)
void xcorr_dw_kernel(const float* __restrict__ z,
                     const float* __restrict__ x,
                     float* __restrict__ out) {
    const int s   = blockIdx.x;      // slice index = b*C + c
    const int tid = threadIdx.x;

    __shared__ float xs[XH * XW];    // 961 floats, row stride 31 (odd -> few bank conflicts)
    __shared__ float zs[KH * KW];    // 49 floats

    const float* __restrict__ xg = x + (size_t)s * (XH * XW);
    const float* __restrict__ zg = z + (size_t)s * (KH * KW);

    // Cooperative staging: coalesced b32 loads.
    for (int idx = tid; idx < XH * XW; idx += 128) xs[idx] = xg[idx];
    if (tid < KH * KW) zs[tid] = zg[tid];
    __syncthreads();

    if (tid < 125) {
        // Broadcast z into registers once (conflict-free same-address reads).
        float zr[KH * KW];
        #pragma unroll
        for (int k = 0; k < KH * KW; ++k) zr[k] = zs[k];

        const int oy  = tid / 5;          // output row 0..24
        const int ox0 = (tid % 5) * 5;    // output col start {0,5,10,15,20}

        float acc[5] = {0.f, 0.f, 0.f, 0.f, 0.f};
        #pragma unroll
        for (int i = 0; i < KH; ++i) {
            const int rowbase = (oy + i) * XW + ox0;
            float r[KW + 4];              // 11 consecutive x values
            #pragma unroll
            for (int j = 0; j < KW + 4; ++j) r[j] = xs[rowbase + j];
            #pragma unroll
            for (int j = 0; j < KW; ++j) {
                const float w = zr[i * KW + j];
                #pragma unroll
                for (int k = 0; k < 5; ++k)
                    acc[k] = fmaf(r[j + k], w, acc[k]);
            }
        }

        // Thread p writes out[5p .. 5p+4]: block output is fully contiguous,
        // L2 write-combines the stride-20B lane pattern across the 5 stores.
        float* __restrict__ og = out + (size_t)s * (OH * OW) + tid * 5;
        #pragma unroll
        for (int k = 0; k < 5; ++k) og[k] = acc[k] * 0.001f;
    }
}

extern "C" void kernel_launch(void* const* d_in, const int* in_sizes, int n_in,
                              void* d_out, int out_size, void* d_ws, size_t ws_size,
                              hipStream_t stream) {
    const float* z = (const float*)d_in[0];   // (64,256,7,7)
    const float* x = (const float*)d_in[1];   // (64,256,31,31)
    float* out = (float*)d_out;               // (64,256,25,25)
    xcorr_dw_kernel<<<dim3(NSLICE), dim3(128), 0, stream>>>(z, x, out);
}

// Round 2
// 126.292 us; speedup vs baseline: 1.0377x; 1.0377x over previous
//
#include <hip/hip_runtime.h>

// Depthwise cross-correlation: z (64,256,7,7) over x (64,256,31,31) VALID
// -> out (64,256,25,25), scaled 0.001.
//
// Round 2: LDS-throughput was the bottleneck (49 us, ~105k LDS cycles/CU).
// Fix: 2D register blocking. Each thread computes a 5x5 output tile:
// 121 LDS x-reads per 25 outputs (4.84/out vs 15.4/out before), z held in
// 49 VGPRs. 5 slices per 128-thread block (25 threads/slice, 125 active).
// x staged with row stride 35: bank = (5*tx + 15*ty) mod 32 -> max 2-way
// within a 25-lane slice group (2-way is free on gfx950, m136).

#define KH 7
#define KW 7
#define XH 31
#define XW 31
#define OH 25
#define OW 25
#define NSLICE (64 * 256)
#define SPB 5               // slices per block
#define THREADS 128
#define XSTRIDE 35          // padded LDS row stride (floats)
#define XSLICE (XH * XSTRIDE)   // 1085 floats per slice

__global__ __launch_bounds__(THREADS)
void xcorr_dw_kernel(const float* __restrict__ z,
                     const float* __restrict__ x,
                     float* __restrict__ out) {
    const int tid = threadIdx.x;
    const int base_slice = blockIdx.x * SPB;
    const int nsl = min(SPB, NSLICE - base_slice);

    __shared__ float xs[SPB * XSLICE];   // 5425 floats = 21.7 KB
    __shared__ float zs[SPB * KH * KW];  // 245 floats

    // ---- Stage: 5 slices of x are contiguous in global; remap into the
    // padded LDS layout. Coalesced dword loads.
    const float* __restrict__ xg = x + (size_t)base_slice * (XH * XW);
    const float* __restrict__ zg = z + (size_t)base_slice * (KH * KW);
    const int nx = nsl * (XH * XW);
    for (int idx = tid; idx < nx; idx += THREADS) {
        const int sl  = idx / (XH * XW);
        const int rem = idx - sl * (XH * XW);
        const int row = rem / XW;
        const int col = rem - row * XW;
        xs[sl * XSLICE + row * XSTRIDE + col] = xg[idx];
    }
    const int nz = nsl * (KH * KW);
    for (int idx = tid; idx < nz; idx += THREADS) zs[idx] = zg[idx];
    __syncthreads();

    // ---- Compute: thread -> (slice, 5x5 tile)
    const int sl = tid / 25;         // 0..5 (5 => inactive lanes 125..127)
    const int tt = tid - sl * 25;    // tile id within slice
    if (sl < nsl) {
        float zr[KH * KW];
        #pragma unroll
        for (int k = 0; k < KH * KW; ++k) zr[k] = zs[sl * (KH * KW) + k];

        const int oy0 = (tt / 5) * 5;   // tile row origin
        const int ox0 = (tt % 5) * 5;   // tile col origin
        const float* __restrict__ xsp = &xs[sl * XSLICE + oy0 * XSTRIDE + ox0];

        float acc[5][5] = {};
        // Sweep the 11 x-rows of the tile's footprint once each.
        #pragma unroll
        for (int r = 0; r < 11; ++r) {
            float xr[11];
            #pragma unroll
            for (int c = 0; c < 11; ++c) xr[c] = xsp[r * XSTRIDE + c];
            #pragma unroll
            for (int a = 0; a < 5; ++a) {
                const int i = r - a;             // kernel row feeding out-row a
                if (i >= 0 && i < KH) {
                    #pragma unroll
                    for (int j = 0; j < KW; ++j) {
                        const float w = zr[i * KW + j];
                        #pragma unroll
                        for (int b = 0; b < 5; ++b)
                            acc[a][b] = fmaf(xr[j + b], w, acc[a][b]);
                    }
                }
            }
        }

        float* __restrict__ og =
            out + (size_t)(base_slice + sl) * (OH * OW) + oy0 * OW + ox0;
        #pragma unroll
        for (int a = 0; a < 5; ++a) {
            #pragma unroll
            for (int b = 0; b < 5; ++b)
                og[a * OW + b] = acc[a][b] * 0.001f;
        }
    }
}

extern "C" void kernel_launch(void* const* d_in, const int* in_sizes, int n_in,
                              void* d_out, int out_size, void* d_ws, size_t ws_size,
                              hipStream_t stream) {
    const float* z = (const float*)d_in[0];   // (64,256,7,7)
    const float* x = (const float*)d_in[1];   // (64,256,31,31)
    float* out = (float*)d_out;               // (64,256,25,25)
    const int nblk = (NSLICE + SPB - 1) / SPB;   // 3277
    xcorr_dw_kernel<<<dim3(nblk), dim3(THREADS), 0, stream>>>(z, x, out);
}